// Round 5
// baseline (347.702 us; speedup 1.0000x reference)
//
#include <hip/hip_runtime.h>

typedef __attribute__((ext_vector_type(8))) short short8;
typedef __attribute__((ext_vector_type(4))) float f32x4;
typedef __attribute__((ext_vector_type(4))) unsigned short u16x4;

#define GLOAD16(g, l)                                                          \
  __builtin_amdgcn_global_load_lds(                                            \
      (const __attribute__((address_space(1))) unsigned int*)(g),              \
      (__attribute__((address_space(3))) unsigned int*)(l), 16, 0, 0)

__device__ __forceinline__ unsigned short f2bf(float f) {
  unsigned int u = __float_as_uint(f);
  u += 0x7FFFu + ((u >> 16) & 1u);   // RNE
  return (unsigned short)(u >> 16);
}
__device__ __forceinline__ float bf2f(unsigned short h) {
  return __uint_as_float(((unsigned int)h) << 16);
}

// ---------------------------------------------------------------- mix / bmix
__global__ void mix_kernel(const float* __restrict__ amp,
                           const float* __restrict__ phase,
                           const float* __restrict__ bias,
                           float* __restrict__ mix, float* __restrict__ bmix) {
  int q = blockIdx.x * blockDim.x + threadIdx.x;  // 0..1023
  float a[16];
  float mx = -1e30f;
  for (int s = 0; s < 16; ++s) {
    a[s] = amp[s * 1024 + q];
    mx = fmaxf(mx, a[s]);
  }
  float sum = 0.f;
  for (int s = 0; s < 16; ++s) {
    a[s] = __expf(a[s] - mx);
    sum += a[s];
  }
  float inv = 1.f / sum;
  for (int s = 0; s < 16; ++s) {
    float m = a[s] * inv * cosf(phase[s * 1024 + q]);
    mix[s * 1024 + q] = m;
    bmix[s * 1024 + q] = bias[s * 1024 + q] * m;
  }
}

// ---------------------------------------------------------------- cast x->bf16
__global__ void cast_x_kernel(const float* __restrict__ x,
                              unsigned short* __restrict__ xb) {
  int i = (blockIdx.x * blockDim.x + threadIdx.x) * 4;
  float4 v = *(const float4*)(x + i);
  union { unsigned short h[4]; uint2 u; } o;
  o.h[0] = f2bf(v.x); o.h[1] = f2bf(v.y); o.h[2] = f2bf(v.z); o.h[3] = f2bf(v.w);
  *(uint2*)(xb + i) = o.u;
}

// ------------------------------------------------- transpose+cast W -> Wt bf16
__global__ __launch_bounds__(256) void transpose_w_kernel(
    const float* __restrict__ W, unsigned short* __restrict__ Wt) {
  __shared__ unsigned short tile[64][66];
  const int s = blockIdx.z;
  const int q0 = blockIdx.x * 64, i0 = blockIdx.y * 64;
  const int t = threadIdx.x;
  const float* Ws = W + (size_t)s * 1048576;
  unsigned short* Wts = Wt + (size_t)s * 1048576;
  const int rq = t & 63, ri = t >> 6;
  #pragma unroll
  for (int p = 0; p < 16; ++p)
    tile[p * 4 + ri][rq] = f2bf(Ws[(size_t)(i0 + p * 4 + ri) * 1024 + q0 + rq]);
  __syncthreads();
  const int wq = t >> 3, wi = (t & 7) * 8;
  #pragma unroll
  for (int o = 0; o < 2; ++o) {
    union { unsigned short h[8]; short8 v; } u;
    #pragma unroll
    for (int e = 0; e < 8; ++e) u.h[e] = tile[wi + e][o * 32 + wq];
    *(short8*)(Wts + (size_t)(q0 + o * 32 + wq) * 1024 + i0 + wi) = u.v;
  }
}

// ---------------------------------------------------------------- bf16 GEMM
// R1 structure (measured 215us): 128x128 tile, BK=32, 4 waves (2x2),
// double-buffered LDS, vmcnt(0)+syncthreads per K-step, ~3 blocks/CU TLP.
// R5 deltas: (a) bf16 sup store (halves write bytes), (b) XCD-aware block
// mapping: xcd = bx%8, by-inner => ~3 B-panels resident per XCD (0.75MB,
// L2-hit) while A (8MB total) stays L3-resident.
template <bool BF16SUP>
__global__ __launch_bounds__(256) void gemm_kernel(
    const unsigned short* __restrict__ xb, const unsigned short* __restrict__ wt,
    const float* __restrict__ mix, const float* __restrict__ bmix,
    float* __restrict__ outf, unsigned short* __restrict__ sup) {
  __shared__ __align__(16) unsigned short Abuf[2][128 * 32];
  __shared__ __align__(16) unsigned short Bbuf[2][128 * 32];

  const int tid = threadIdx.x;
  const int lane = tid & 63;
  const int wv = tid >> 6;
  const int wm = wv >> 1, wn = wv & 1;

  // block mapping: id -> (bx, by) grouped so each XCD's resident blocks
  // share few B panels.  bx in [0,128), by in [0,32).
  const int id = blockIdx.x;
  const int xcd = id & 7;
  const int c = id >> 3;               // 0..511 per XCD
  const int bx = (c >> 5) * 8 + xcd;   // B-panel index (16 per XCD, slow)
  const int by = c & 31;               // A-panel index (fast)
  const int m0 = by * 128;
  const int n0 = bx * 128;

  // staging geometry: chunk c covers tile row c/4, 8 bf16 at col (c%4)*8
  const int c0 = tid, c1 = tid + 256;
  const int r0 = c0 >> 2, k80 = (c0 & 3) * 8;
  const int r1 = c1 >> 2, k81 = (c1 & 3) * 8;
  const unsigned short* ga0 = xb + (size_t)(m0 + r0) * 1024 + k80;
  const unsigned short* ga1 = xb + (size_t)(m0 + r1) * 1024 + k81;
  const unsigned short* gb0 = wt + (size_t)(n0 + r0) * 1024 + k80;
  const unsigned short* gb1 = wt + (size_t)(n0 + r1) * 1024 + k81;

  f32x4 acc[4][4];
  #pragma unroll
  for (int i = 0; i < 4; ++i)
    #pragma unroll
    for (int j = 0; j < 4; ++j) acc[i][j] = (f32x4){0.f, 0.f, 0.f, 0.f};

  // prologue: stage k-tile 0 into buffer 0
  GLOAD16(ga0, &Abuf[0][c0 * 8]);
  GLOAD16(ga1, &Abuf[0][c1 * 8]);
  GLOAD16(gb0, &Bbuf[0][c0 * 8]);
  GLOAD16(gb1, &Bbuf[0][c1 * 8]);
  asm volatile("s_waitcnt vmcnt(0)" ::: "memory");
  __syncthreads();

  const int lr = lane & 15;
  const int lk = (lane >> 4) * 8;
  int cur = 0;
  for (int kt = 0; kt < 32; ++kt) {
    if (kt < 31) {
      const int ko = (kt + 1) * 32;
      GLOAD16(ga0 + ko, &Abuf[cur ^ 1][c0 * 8]);
      GLOAD16(ga1 + ko, &Abuf[cur ^ 1][c1 * 8]);
      GLOAD16(gb0 + ko, &Bbuf[cur ^ 1][c0 * 8]);
      GLOAD16(gb1 + ko, &Bbuf[cur ^ 1][c1 * 8]);
    }
    short8 af[4], bfr[4];
    #pragma unroll
    for (int mi = 0; mi < 4; ++mi)
      af[mi] = *(const short8*)&Abuf[cur][(wm * 64 + mi * 16 + lr) * 32 + lk];
    #pragma unroll
    for (int ni = 0; ni < 4; ++ni)
      bfr[ni] = *(const short8*)&Bbuf[cur][(wn * 64 + ni * 16 + lr) * 32 + lk];
    #pragma unroll
    for (int mi = 0; mi < 4; ++mi)
      #pragma unroll
      for (int ni = 0; ni < 4; ++ni)
        acc[mi][ni] = __builtin_amdgcn_mfma_f32_16x16x32_bf16(
            af[mi], bfr[ni], acc[mi][ni], 0, 0, 0);
    asm volatile("s_waitcnt vmcnt(0)" ::: "memory");
    __syncthreads();
    cur ^= 1;
  }

  // epilogue: sup = acc*mix + bmix
  #pragma unroll
  for (int ni = 0; ni < 4; ++ni) {
    const int n = n0 + wn * 64 + ni * 16 + lr;
    const float mv = mix[n];
    const float bv = bmix[n];
    #pragma unroll
    for (int mi = 0; mi < 4; ++mi) {
      const int m = m0 + wm * 64 + mi * 16 + (lane >> 4) * 4;
      #pragma unroll
      for (int r = 0; r < 4; ++r) {
        float v = acc[mi][ni][r] * mv + bv;
        if (BF16SUP)
          sup[(size_t)(m + r) * 16384 + n] = f2bf(v);
        else
          outf[(size_t)(m + r) * 16384 + n] = v;
      }
    }
  }
}

// ------------------------------------------------------- LN from bf16 sup
__global__ __launch_bounds__(256) void ln_bf16_kernel(
    const unsigned short* __restrict__ sup, float* __restrict__ out,
    const float* __restrict__ gamma, const float* __restrict__ beta) {
  __shared__ float red[8];
  const int t = threadIdx.x;
  const size_t base = (size_t)blockIdx.x * 1024;
  u16x4 raw = *(const u16x4*)(sup + base + t * 4);
  float v[4];
  #pragma unroll
  for (int j = 0; j < 4; ++j) v[j] = bf2f(raw[j]);
  float s = v[0] + v[1] + v[2] + v[3];
  float ss = v[0] * v[0] + v[1] * v[1] + v[2] * v[2] + v[3] * v[3];
  #pragma unroll
  for (int m = 32; m >= 1; m >>= 1) {
    s += __shfl_xor(s, m);
    ss += __shfl_xor(ss, m);
  }
  const int wv = t >> 6;
  if ((t & 63) == 0) { red[wv * 2] = s; red[wv * 2 + 1] = ss; }
  __syncthreads();
  const float S = red[0] + red[2] + red[4] + red[6];
  const float SS = red[1] + red[3] + red[5] + red[7];
  const float mean = S * (1.0f / 1024.0f);
  const float var = SS * (1.0f / 1024.0f) - mean * mean;
  const float rstd = rsqrtf(var + 1e-5f);
  const float4 g = *(const float4*)(gamma + t * 4);
  const float4 b = *(const float4*)(beta + t * 4);
  float4 o;
  o.x = (v[0] - mean) * rstd * g.x + b.x;
  o.y = (v[1] - mean) * rstd * g.y + b.y;
  o.z = (v[2] - mean) * rstd * g.z + b.z;
  o.w = (v[3] - mean) * rstd * g.w + b.w;
  *(float4*)(out + base + t * 4) = o;
}

// ------------------------------------------------------- in-place f32 LN
__global__ __launch_bounds__(256) void ln_kernel(float* __restrict__ out,
                                                 const float* __restrict__ gamma,
                                                 const float* __restrict__ beta) {
  __shared__ float red[8];
  const int t = threadIdx.x;
  const size_t base = (size_t)blockIdx.x * 1024;
  float4 v = *(const float4*)(out + base + t * 4);
  float s = v.x + v.y + v.z + v.w;
  float ss = v.x * v.x + v.y * v.y + v.z * v.z + v.w * v.w;
  #pragma unroll
  for (int m = 32; m >= 1; m >>= 1) {
    s += __shfl_xor(s, m);
    ss += __shfl_xor(ss, m);
  }
  const int wv = t >> 6;
  if ((t & 63) == 0) { red[wv * 2] = s; red[wv * 2 + 1] = ss; }
  __syncthreads();
  const float S = red[0] + red[2] + red[4] + red[6];
  const float SS = red[1] + red[3] + red[5] + red[7];
  const float mean = S * (1.0f / 1024.0f);
  const float var = SS * (1.0f / 1024.0f) - mean * mean;
  const float rstd = rsqrtf(var + 1e-5f);
  const float4 g = *(const float4*)(gamma + t * 4);
  const float4 b = *(const float4*)(beta + t * 4);
  float4 o;
  o.x = (v.x - mean) * rstd * g.x + b.x;
  o.y = (v.y - mean) * rstd * g.y + b.y;
  o.z = (v.z - mean) * rstd * g.z + b.z;
  o.w = (v.w - mean) * rstd * g.w + b.w;
  *(float4*)(out + base + t * 4) = o;
}

extern "C" void kernel_launch(void* const* d_in, const int* in_sizes, int n_in,
                              void* d_out, int out_size, void* d_ws, size_t ws_size,
                              hipStream_t stream) {
  (void)in_sizes; (void)n_in; (void)out_size;
  const float* x     = (const float*)d_in[0];  // [4096,1024]
  const float* W     = (const float*)d_in[1];  // [16,1024,1024]
  const float* bias  = (const float*)d_in[2];  // [16,1024]
  const float* amp   = (const float*)d_in[3];  // [16,1024]
  const float* phase = (const float*)d_in[4];  // [16,1024]
  const float* gamma = (const float*)d_in[5];  // [1024]
  const float* beta  = (const float*)d_in[6];  // [1024]
  float* out = (float*)d_out;                  // [4096,16,1024] = 256 MiB

  const bool big = ws_size >= (size_t)134217728ULL;  // bf16 sup fits in ws

  unsigned short *Wt, *xbuf, *supb = nullptr;
  float *mixp, *bmixp;
  if (big) {
    // scratch Wt/xb/mix live in d_out (fully rewritten by LN afterwards);
    // ws holds bf16 sup (exactly 128 MiB)
    char* ob = (char*)d_out;
    Wt    = (unsigned short*)ob;                    // 32 MiB
    xbuf  = (unsigned short*)(ob + 33554432);       //  8 MiB
    mixp  = (float*)(ob + 41943040);                // 64 KiB
    bmixp = mixp + 16384;                           // 64 KiB
    supb  = (unsigned short*)d_ws;                  // 128 MiB
  } else {
    char* ws = (char*)d_ws;
    Wt    = (unsigned short*)ws;                    // 32 MiB
    xbuf  = (unsigned short*)(ws + 33554432);       //  8 MiB
    mixp  = (float*)(ws + 33554432 + 8388608);      // 64 KiB
    bmixp = mixp + 16384;                           // 64 KiB
  }

  hipLaunchKernelGGL(mix_kernel, dim3(4), dim3(256), 0, stream, amp, phase, bias, mixp, bmixp);
  hipLaunchKernelGGL(cast_x_kernel, dim3(4096), dim3(256), 0, stream, x, xbuf);
  hipLaunchKernelGGL(transpose_w_kernel, dim3(16, 16, 16), dim3(256), 0, stream, W, Wt);
  if (big) {
    hipLaunchKernelGGL((gemm_kernel<true>), dim3(4096), dim3(256), 0, stream,
                       xbuf, Wt, mixp, bmixp, out, supb);
    hipLaunchKernelGGL(ln_bf16_kernel, dim3(65536), dim3(256), 0, stream,
                       supb, out, gamma, beta);
  } else {
    hipLaunchKernelGGL((gemm_kernel<false>), dim3(4096), dim3(256), 0, stream,
                       xbuf, Wt, mixp, bmixp, out, nullptr);
    hipLaunchKernelGGL(ln_kernel, dim3(65536), dim3(256), 0, stream, out, gamma, beta);
  }
}

// Round 6
// 319.843 us; speedup vs baseline: 1.0871x; 1.0871x over previous
//
#include <hip/hip_runtime.h>

typedef __attribute__((ext_vector_type(8))) short short8;
typedef __attribute__((ext_vector_type(4))) float f32x4;
typedef __attribute__((ext_vector_type(4))) unsigned short u16x4;

#define GLOAD16(g, l)                                                          \
  __builtin_amdgcn_global_load_lds(                                            \
      (const __attribute__((address_space(1))) unsigned int*)(g),              \
      (__attribute__((address_space(3))) unsigned int*)(l), 16, 0, 0)

__device__ __forceinline__ unsigned short f2bf(float f) {
  unsigned int u = __float_as_uint(f);
  u += 0x7FFFu + ((u >> 16) & 1u);   // RNE
  return (unsigned short)(u >> 16);
}
__device__ __forceinline__ float bf2f(unsigned short h) {
  return __uint_as_float(((unsigned int)h) << 16);
}

// ---------------------------------------------------------------- mix / bmix
__global__ void mix_kernel(const float* __restrict__ amp,
                           const float* __restrict__ phase,
                           const float* __restrict__ bias,
                           float* __restrict__ mix, float* __restrict__ bmix) {
  int q = blockIdx.x * blockDim.x + threadIdx.x;  // 0..1023
  float a[16];
  float mx = -1e30f;
  for (int s = 0; s < 16; ++s) {
    a[s] = amp[s * 1024 + q];
    mx = fmaxf(mx, a[s]);
  }
  float sum = 0.f;
  for (int s = 0; s < 16; ++s) {
    a[s] = __expf(a[s] - mx);
    sum += a[s];
  }
  float inv = 1.f / sum;
  for (int s = 0; s < 16; ++s) {
    float m = a[s] * inv * cosf(phase[s * 1024 + q]);
    mix[s * 1024 + q] = m;
    bmix[s * 1024 + q] = bias[s * 1024 + q] * m;
  }
}

// ---------------------------------------------------------------- cast x->bf16
__global__ void cast_x_kernel(const float* __restrict__ x,
                              unsigned short* __restrict__ xb) {
  int i = (blockIdx.x * blockDim.x + threadIdx.x) * 4;
  float4 v = *(const float4*)(x + i);
  union { unsigned short h[4]; uint2 u; } o;
  o.h[0] = f2bf(v.x); o.h[1] = f2bf(v.y); o.h[2] = f2bf(v.z); o.h[3] = f2bf(v.w);
  *(uint2*)(xb + i) = o.u;
}

// ------------------------------------------- transpose+cast+scale W -> Wt bf16
// Wt[s][q][i] = bf16( W[s][i][q] * mix[s][q] )   (mix folded into B operand)
__global__ __launch_bounds__(256) void transpose_w_kernel(
    const float* __restrict__ W, const float* __restrict__ mix,
    unsigned short* __restrict__ Wt) {
  __shared__ unsigned short tile[64][66];
  const int s = blockIdx.z;
  const int q0 = blockIdx.x * 64, i0 = blockIdx.y * 64;
  const int t = threadIdx.x;
  const float* Ws = W + (size_t)s * 1048576;
  unsigned short* Wts = Wt + (size_t)s * 1048576;
  const int rq = t & 63, ri = t >> 6;
  const float mv = mix[s * 1024 + q0 + rq];
  #pragma unroll
  for (int p = 0; p < 16; ++p)
    tile[p * 4 + ri][rq] =
        f2bf(Ws[(size_t)(i0 + p * 4 + ri) * 1024 + q0 + rq] * mv);
  __syncthreads();
  const int wq = t >> 3, wi = (t & 7) * 8;
  #pragma unroll
  for (int o = 0; o < 2; ++o) {
    union { unsigned short h[8]; short8 v; } u;
    #pragma unroll
    for (int e = 0; e < 8; ++e) u.h[e] = tile[wi + e][o * 32 + wq];
    *(short8*)(Wts + (size_t)(q0 + o * 32 + wq) * 1024 + i0 + wi) = u.v;
  }
}

// ---------------------------------------------------------------- bf16 GEMM
// R1 structure verbatim (measured 215us / 639 TF; L2-fill-bound at ~2.4TB/s):
// 128x128 tile, BK=32, 4 waves (2x2), dbuf LDS, vmcnt(0)+sync per K-step,
// grid(128,32) bx-fast (the mapping R5 proved optimal for L2).
// Deltas: bf16 sup stores (halves write traffic); mix pre-folded into Wt so
// epilogue is acc + bmix only.
template <bool BF16SUP>
__global__ __launch_bounds__(256) void gemm_kernel(
    const unsigned short* __restrict__ xb, const unsigned short* __restrict__ wt,
    const float* __restrict__ bmix,
    float* __restrict__ outf, unsigned short* __restrict__ sup) {
  __shared__ __align__(16) unsigned short Abuf[2][128 * 32];
  __shared__ __align__(16) unsigned short Bbuf[2][128 * 32];

  const int tid = threadIdx.x;
  const int lane = tid & 63;
  const int wv = tid >> 6;
  const int wm = wv >> 1, wn = wv & 1;
  const int m0 = blockIdx.y * 128;
  const int n0 = blockIdx.x * 128;

  const int c0 = tid, c1 = tid + 256;
  const int r0 = c0 >> 2, k80 = (c0 & 3) * 8;
  const int r1 = c1 >> 2, k81 = (c1 & 3) * 8;
  const unsigned short* ga0 = xb + (size_t)(m0 + r0) * 1024 + k80;
  const unsigned short* ga1 = xb + (size_t)(m0 + r1) * 1024 + k81;
  const unsigned short* gb0 = wt + (size_t)(n0 + r0) * 1024 + k80;
  const unsigned short* gb1 = wt + (size_t)(n0 + r1) * 1024 + k81;

  f32x4 acc[4][4];
  #pragma unroll
  for (int i = 0; i < 4; ++i)
    #pragma unroll
    for (int j = 0; j < 4; ++j) acc[i][j] = (f32x4){0.f, 0.f, 0.f, 0.f};

  GLOAD16(ga0, &Abuf[0][c0 * 8]);
  GLOAD16(ga1, &Abuf[0][c1 * 8]);
  GLOAD16(gb0, &Bbuf[0][c0 * 8]);
  GLOAD16(gb1, &Bbuf[0][c1 * 8]);
  asm volatile("s_waitcnt vmcnt(0)" ::: "memory");
  __syncthreads();

  const int lr = lane & 15;
  const int lk = (lane >> 4) * 8;
  int cur = 0;
  for (int kt = 0; kt < 32; ++kt) {
    if (kt < 31) {
      const int ko = (kt + 1) * 32;
      GLOAD16(ga0 + ko, &Abuf[cur ^ 1][c0 * 8]);
      GLOAD16(ga1 + ko, &Abuf[cur ^ 1][c1 * 8]);
      GLOAD16(gb0 + ko, &Bbuf[cur ^ 1][c0 * 8]);
      GLOAD16(gb1 + ko, &Bbuf[cur ^ 1][c1 * 8]);
    }
    short8 af[4], bfr[4];
    #pragma unroll
    for (int mi = 0; mi < 4; ++mi)
      af[mi] = *(const short8*)&Abuf[cur][(wm * 64 + mi * 16 + lr) * 32 + lk];
    #pragma unroll
    for (int ni = 0; ni < 4; ++ni)
      bfr[ni] = *(const short8*)&Bbuf[cur][(wn * 64 + ni * 16 + lr) * 32 + lk];
    #pragma unroll
    for (int mi = 0; mi < 4; ++mi)
      #pragma unroll
      for (int ni = 0; ni < 4; ++ni)
        acc[mi][ni] = __builtin_amdgcn_mfma_f32_16x16x32_bf16(
            af[mi], bfr[ni], acc[mi][ni], 0, 0, 0);
    asm volatile("s_waitcnt vmcnt(0)" ::: "memory");
    __syncthreads();
    cur ^= 1;
  }

  // epilogue: sup = acc + bmix  (mix already folded into Wt)
  #pragma unroll
  for (int ni = 0; ni < 4; ++ni) {
    const int n = n0 + wn * 64 + ni * 16 + lr;
    const float bv = bmix[n];
    #pragma unroll
    for (int mi = 0; mi < 4; ++mi) {
      const int m = m0 + wm * 64 + mi * 16 + (lane >> 4) * 4;
      #pragma unroll
      for (int r = 0; r < 4; ++r) {
        float v = acc[mi][ni][r] + bv;
        if (BF16SUP)
          sup[(size_t)(m + r) * 16384 + n] = f2bf(v);
        else
          outf[(size_t)(m + r) * 16384 + n] = v;
      }
    }
  }
}

// ------------------------------------------------------- LN from bf16 sup
__global__ __launch_bounds__(256) void ln_bf16_kernel(
    const unsigned short* __restrict__ sup, float* __restrict__ out,
    const float* __restrict__ gamma, const float* __restrict__ beta) {
  __shared__ float red[8];
  const int t = threadIdx.x;
  const size_t base = (size_t)blockIdx.x * 1024;
  u16x4 raw = *(const u16x4*)(sup + base + t * 4);
  float v[4];
  #pragma unroll
  for (int j = 0; j < 4; ++j) v[j] = bf2f(raw[j]);
  float s = v[0] + v[1] + v[2] + v[3];
  float ss = v[0] * v[0] + v[1] * v[1] + v[2] * v[2] + v[3] * v[3];
  #pragma unroll
  for (int m = 32; m >= 1; m >>= 1) {
    s += __shfl_xor(s, m);
    ss += __shfl_xor(ss, m);
  }
  const int wv = t >> 6;
  if ((t & 63) == 0) { red[wv * 2] = s; red[wv * 2 + 1] = ss; }
  __syncthreads();
  const float S = red[0] + red[2] + red[4] + red[6];
  const float SS = red[1] + red[3] + red[5] + red[7];
  const float mean = S * (1.0f / 1024.0f);
  const float var = SS * (1.0f / 1024.0f) - mean * mean;
  const float rstd = rsqrtf(var + 1e-5f);
  const float4 g = *(const float4*)(gamma + t * 4);
  const float4 b = *(const float4*)(beta + t * 4);
  float4 o;
  o.x = (v[0] - mean) * rstd * g.x + b.x;
  o.y = (v[1] - mean) * rstd * g.y + b.y;
  o.z = (v[2] - mean) * rstd * g.z + b.z;
  o.w = (v[3] - mean) * rstd * g.w + b.w;
  *(float4*)(out + base + t * 4) = o;
}

// ------------------------------------------------------- in-place f32 LN
__global__ __launch_bounds__(256) void ln_kernel(float* __restrict__ out,
                                                 const float* __restrict__ gamma,
                                                 const float* __restrict__ beta) {
  __shared__ float red[8];
  const int t = threadIdx.x;
  const size_t base = (size_t)blockIdx.x * 1024;
  float4 v = *(const float4*)(out + base + t * 4);
  float s = v.x + v.y + v.z + v.w;
  float ss = v.x * v.x + v.y * v.y + v.z * v.z + v.w * v.w;
  #pragma unroll
  for (int m = 32; m >= 1; m >>= 1) {
    s += __shfl_xor(s, m);
    ss += __shfl_xor(ss, m);
  }
  const int wv = t >> 6;
  if ((t & 63) == 0) { red[wv * 2] = s; red[wv * 2 + 1] = ss; }
  __syncthreads();
  const float S = red[0] + red[2] + red[4] + red[6];
  const float SS = red[1] + red[3] + red[5] + red[7];
  const float mean = S * (1.0f / 1024.0f);
  const float var = SS * (1.0f / 1024.0f) - mean * mean;
  const float rstd = rsqrtf(var + 1e-5f);
  const float4 g = *(const float4*)(gamma + t * 4);
  const float4 b = *(const float4*)(beta + t * 4);
  float4 o;
  o.x = (v.x - mean) * rstd * g.x + b.x;
  o.y = (v.y - mean) * rstd * g.y + b.y;
  o.z = (v.z - mean) * rstd * g.z + b.z;
  o.w = (v.w - mean) * rstd * g.w + b.w;
  *(float4*)(out + base + t * 4) = o;
}

extern "C" void kernel_launch(void* const* d_in, const int* in_sizes, int n_in,
                              void* d_out, int out_size, void* d_ws, size_t ws_size,
                              hipStream_t stream) {
  (void)in_sizes; (void)n_in; (void)out_size;
  const float* x     = (const float*)d_in[0];  // [4096,1024]
  const float* W     = (const float*)d_in[1];  // [16,1024,1024]
  const float* bias  = (const float*)d_in[2];  // [16,1024]
  const float* amp   = (const float*)d_in[3];  // [16,1024]
  const float* phase = (const float*)d_in[4];  // [16,1024]
  const float* gamma = (const float*)d_in[5];  // [1024]
  const float* beta  = (const float*)d_in[6];  // [1024]
  float* out = (float*)d_out;                  // [4096,16,1024] = 256 MiB

  const bool big = ws_size >= (size_t)134217728ULL;  // bf16 sup fits in ws

  unsigned short *Wt, *xbuf, *supb = nullptr;
  float *mixp, *bmixp;
  if (big) {
    // scratch Wt/xb/mix live in d_out (fully rewritten by LN afterwards);
    // ws holds bf16 sup (exactly 128 MiB)
    char* ob = (char*)d_out;
    Wt    = (unsigned short*)ob;                    // 32 MiB
    xbuf  = (unsigned short*)(ob + 33554432);       //  8 MiB
    mixp  = (float*)(ob + 41943040);                // 64 KiB
    bmixp = mixp + 16384;                           // 64 KiB
    supb  = (unsigned short*)d_ws;                  // 128 MiB
  } else {
    char* ws = (char*)d_ws;
    Wt    = (unsigned short*)ws;                    // 32 MiB
    xbuf  = (unsigned short*)(ws + 33554432);       //  8 MiB
    mixp  = (float*)(ws + 33554432 + 8388608);      // 64 KiB
    bmixp = mixp + 16384;                           // 64 KiB
  }

  hipLaunchKernelGGL(mix_kernel, dim3(4), dim3(256), 0, stream, amp, phase, bias, mixp, bmixp);
  hipLaunchKernelGGL(cast_x_kernel, dim3(4096), dim3(256), 0, stream, x, xbuf);
  hipLaunchKernelGGL(transpose_w_kernel, dim3(16, 16, 16), dim3(256), 0, stream, W, mixp, Wt);
  if (big) {
    hipLaunchKernelGGL((gemm_kernel<true>), dim3(128, 32), dim3(256), 0, stream,
                       xbuf, Wt, bmixp, out, supb);
    hipLaunchKernelGGL(ln_bf16_kernel, dim3(65536), dim3(256), 0, stream,
                       supb, out, gamma, beta);
  } else {
    hipLaunchKernelGGL((gemm_kernel<false>), dim3(128, 32), dim3(256), 0, stream,
                       xbuf, Wt, bmixp, out, nullptr);
    hipLaunchKernelGGL(ln_kernel, dim3(65536), dim3(256), 0, stream, out, gamma, beta);
  }
}

// Round 8
// 302.554 us; speedup vs baseline: 1.1492x; 1.0571x over previous
//
#include <hip/hip_runtime.h>

typedef __attribute__((ext_vector_type(8))) short short8;
typedef __attribute__((ext_vector_type(4))) float f32x4;
typedef __attribute__((ext_vector_type(4))) unsigned short u16x4;

#define GLOAD16(g, l)                                                          \
  __builtin_amdgcn_global_load_lds(                                            \
      (const __attribute__((address_space(1))) unsigned int*)(g),              \
      (__attribute__((address_space(3))) unsigned int*)(l), 16, 0, 0)

__device__ __forceinline__ unsigned short f2bf(float f) {
  unsigned int u = __float_as_uint(f);
  u += 0x7FFFu + ((u >> 16) & 1u);   // RNE
  return (unsigned short)(u >> 16);
}
__device__ __forceinline__ float bf2f(unsigned short h) {
  return __uint_as_float(((unsigned int)h) << 16);
}

// ---------------------------------------------------------------- mix / bmix
__global__ void mix_kernel(const float* __restrict__ amp,
                           const float* __restrict__ phase,
                           const float* __restrict__ bias,
                           float* __restrict__ mix, float* __restrict__ bmix) {
  int q = blockIdx.x * blockDim.x + threadIdx.x;  // 0..1023
  float a[16];
  float mx = -1e30f;
  for (int s = 0; s < 16; ++s) {
    a[s] = amp[s * 1024 + q];
    mx = fmaxf(mx, a[s]);
  }
  float sum = 0.f;
  for (int s = 0; s < 16; ++s) {
    a[s] = __expf(a[s] - mx);
    sum += a[s];
  }
  float inv = 1.f / sum;
  for (int s = 0; s < 16; ++s) {
    float m = a[s] * inv * cosf(phase[s * 1024 + q]);
    mix[s * 1024 + q] = m;
    bmix[s * 1024 + q] = bias[s * 1024 + q] * m;
  }
}

// ---------------------------------------------------------------- cast x->bf16
__global__ void cast_x_kernel(const float* __restrict__ x,
                              unsigned short* __restrict__ xb) {
  int i = (blockIdx.x * blockDim.x + threadIdx.x) * 4;
  float4 v = *(const float4*)(x + i);
  union { unsigned short h[4]; uint2 u; } o;
  o.h[0] = f2bf(v.x); o.h[1] = f2bf(v.y); o.h[2] = f2bf(v.z); o.h[3] = f2bf(v.w);
  *(uint2*)(xb + i) = o.u;
}

// ------------------------------------------- transpose+cast+scale W -> Wt bf16
// Wt[s][q][i] = bf16( W[s][i][q] * mix[s][q] )
__global__ __launch_bounds__(256) void transpose_w_kernel(
    const float* __restrict__ W, const float* __restrict__ mix,
    unsigned short* __restrict__ Wt) {
  __shared__ unsigned short tile[64][66];
  const int s = blockIdx.z;
  const int q0 = blockIdx.x * 64, i0 = blockIdx.y * 64;
  const int t = threadIdx.x;
  const float* Ws = W + (size_t)s * 1048576;
  unsigned short* Wts = Wt + (size_t)s * 1048576;
  const int rq = t & 63, ri = t >> 6;
  const float mv = mix[s * 1024 + q0 + rq];
  #pragma unroll
  for (int p = 0; p < 16; ++p)
    tile[p * 4 + ri][rq] =
        f2bf(Ws[(size_t)(i0 + p * 4 + ri) * 1024 + q0 + rq] * mv);
  __syncthreads();
  const int wq = t >> 3, wi = (t & 7) * 8;
  #pragma unroll
  for (int o = 0; o < 2; ++o) {
    union { unsigned short h[8]; short8 v; } u;
    #pragma unroll
    for (int e = 0; e < 8; ++e) u.h[e] = tile[wi + e][o * 32 + wq];
    *(short8*)(Wts + (size_t)(q0 + o * 32 + wq) * 1024 + i0 + wi) = u.v;
  }
}

// ---------------------------------------------------------------- bf16 GEMM
// R6 structure (proven 205us) + 3-buffer depth-2 counted prefetch:
// step t stages k-tile t+2 into buf (t+2)%3; end-of-step vmcnt(4) waits only
// for the stage issued one FULL step earlier (latency covered by this step's
// reads+MFMA), then one barrier.  Ledger: WAITV(4) leaves only stage t+2 in
// flight -> buf (t+1)%3 valid after barrier (vmcnt->BAR->read, cross-wave
// safe).  WAR: stage t+2 overwrites buf of step t-1 whose reads completed
// before step t-1's barrier.  LDS 48KB keeps ~3 blocks/CU TLP.
template <bool BF16SUP>
__global__ __launch_bounds__(256) void gemm_kernel(
    const unsigned short* __restrict__ xb, const unsigned short* __restrict__ wt,
    const float* __restrict__ bmix,
    float* __restrict__ outf, unsigned short* __restrict__ sup) {
  __shared__ __align__(16) unsigned short Abuf[3][128 * 32];
  __shared__ __align__(16) unsigned short Bbuf[3][128 * 32];

  const int tid = threadIdx.x;
  const int lane = tid & 63;
  const int wv = tid >> 6;
  const int wm = wv >> 1, wn = wv & 1;
  const int m0 = blockIdx.y * 128;
  const int n0 = blockIdx.x * 128;

  const int c0 = tid, c1 = tid + 256;
  const int r0 = c0 >> 2, k80 = (c0 & 3) * 8;
  const int r1 = c1 >> 2, k81 = (c1 & 3) * 8;
  const unsigned short* ga0 = xb + (size_t)(m0 + r0) * 1024 + k80;
  const unsigned short* ga1 = xb + (size_t)(m0 + r1) * 1024 + k81;
  const unsigned short* gb0 = wt + (size_t)(n0 + r0) * 1024 + k80;
  const unsigned short* gb1 = wt + (size_t)(n0 + r1) * 1024 + k81;

#define STAGE(kt, b) do {                                                      \
    const int _ko = (kt) * 32;                                                 \
    GLOAD16(ga0 + _ko, &Abuf[b][c0 * 8]);                                      \
    GLOAD16(ga1 + _ko, &Abuf[b][c1 * 8]);                                      \
    GLOAD16(gb0 + _ko, &Bbuf[b][c0 * 8]);                                      \
    GLOAD16(gb1 + _ko, &Bbuf[b][c1 * 8]);                                      \
  } while (0)

  f32x4 acc[4][4];
  #pragma unroll
  for (int i = 0; i < 4; ++i)
    #pragma unroll
    for (int j = 0; j < 4; ++j) acc[i][j] = (f32x4){0.f, 0.f, 0.f, 0.f};

  // prologue: stage tiles 0,1; wait tile 0 landed (tile 1 stays in flight)
  STAGE(0, 0);
  STAGE(1, 1);
  asm volatile("s_waitcnt vmcnt(4)" ::: "memory");
  __syncthreads();

  const int lr = lane & 15;
  const int lk = (lane >> 4) * 8;
  int cur = 0;
  for (int kt = 0; kt < 32; ++kt) {
    if (kt < 30) {
      int nb = cur + 2; if (nb >= 3) nb -= 3;
      STAGE(kt + 2, nb);
    }
    short8 af[4], bfr[4];
    #pragma unroll
    for (int mi = 0; mi < 4; ++mi)
      af[mi] = *(const short8*)&Abuf[cur][(wm * 64 + mi * 16 + lr) * 32 + lk];
    #pragma unroll
    for (int ni = 0; ni < 4; ++ni)
      bfr[ni] = *(const short8*)&Bbuf[cur][(wn * 64 + ni * 16 + lr) * 32 + lk];
    #pragma unroll
    for (int mi = 0; mi < 4; ++mi)
      #pragma unroll
      for (int ni = 0; ni < 4; ++ni)
        acc[mi][ni] = __builtin_amdgcn_mfma_f32_16x16x32_bf16(
            af[mi], bfr[ni], acc[mi][ni], 0, 0, 0);
    if (kt < 30) {
      asm volatile("s_waitcnt vmcnt(4)" ::: "memory");  // tile kt+1 landed
    } else {
      asm volatile("s_waitcnt vmcnt(0)" ::: "memory");  // tail drain
    }
    __syncthreads();
    cur += 1; if (cur >= 3) cur = 0;
  }
#undef STAGE

  // epilogue: sup = acc + bmix  (mix folded into Wt)
  #pragma unroll
  for (int ni = 0; ni < 4; ++ni) {
    const int n = n0 + wn * 64 + ni * 16 + lr;
    const float bv = bmix[n];
    #pragma unroll
    for (int mi = 0; mi < 4; ++mi) {
      const int m = m0 + wm * 64 + mi * 16 + (lane >> 4) * 4;
      #pragma unroll
      for (int r = 0; r < 4; ++r) {
        float v = acc[mi][ni][r] + bv;
        if (BF16SUP)
          sup[(size_t)(m + r) * 16384 + n] = f2bf(v);
        else
          outf[(size_t)(m + r) * 16384 + n] = v;
      }
    }
  }
}

// ------------------------------------------------------- LN from bf16 sup
__global__ __launch_bounds__(256) void ln_bf16_kernel(
    const unsigned short* __restrict__ sup, float* __restrict__ out,
    const float* __restrict__ gamma, const float* __restrict__ beta) {
  __shared__ float red[8];
  const int t = threadIdx.x;
  const size_t base = (size_t)blockIdx.x * 1024;
  u16x4 raw = *(const u16x4*)(sup + base + t * 4);
  float v[4];
  #pragma unroll
  for (int j = 0; j < 4; ++j) v[j] = bf2f(raw[j]);
  float s = v[0] + v[1] + v[2] + v[3];
  float ss = v[0] * v[0] + v[1] * v[1] + v[2] * v[2] + v[3] * v[3];
  #pragma unroll
  for (int m = 32; m >= 1; m >>= 1) {
    s += __shfl_xor(s, m);
    ss += __shfl_xor(ss, m);
  }
  const int wv = t >> 6;
  if ((t & 63) == 0) { red[wv * 2] = s; red[wv * 2 + 1] = ss; }
  __syncthreads();
  const float S = red[0] + red[2] + red[4] + red[6];
  const float SS = red[1] + red[3] + red[5] + red[7];
  const float mean = S * (1.0f / 1024.0f);
  const float var = SS * (1.0f / 1024.0f) - mean * mean;
  const float rstd = rsqrtf(var + 1e-5f);
  const float4 g = *(const float4*)(gamma + t * 4);
  const float4 b = *(const float4*)(beta + t * 4);
  float4 o;
  o.x = (v[0] - mean) * rstd * g.x + b.x;
  o.y = (v[1] - mean) * rstd * g.y + b.y;
  o.z = (v[2] - mean) * rstd * g.z + b.z;
  o.w = (v[3] - mean) * rstd * g.w + b.w;
  *(float4*)(out + base + t * 4) = o;
}

// ------------------------------------------------------- in-place f32 LN
__global__ __launch_bounds__(256) void ln_kernel(float* __restrict__ out,
                                                 const float* __restrict__ gamma,
                                                 const float* __restrict__ beta) {
  __shared__ float red[8];
  const int t = threadIdx.x;
  const size_t base = (size_t)blockIdx.x * 1024;
  float4 v = *(const float4*)(out + base + t * 4);
  float s = v.x + v.y + v.z + v.w;
  float ss = v.x * v.x + v.y * v.y + v.z * v.z + v.w * v.w;
  #pragma unroll
  for (int m = 32; m >= 1; m >>= 1) {
    s += __shfl_xor(s, m);
    ss += __shfl_xor(ss, m);
  }
  const int wv = t >> 6;
  if ((t & 63) == 0) { red[wv * 2] = s; red[wv * 2 + 1] = ss; }
  __syncthreads();
  const float S = red[0] + red[2] + red[4] + red[6];
  const float SS = red[1] + red[3] + red[5] + red[7];
  const float mean = S * (1.0f / 1024.0f);
  const float var = SS * (1.0f / 1024.0f) - mean * mean;
  const float rstd = rsqrtf(var + 1e-5f);
  const float4 g = *(const float4*)(gamma + t * 4);
  const float4 b = *(const float4*)(beta + t * 4);
  float4 o;
  o.x = (v.x - mean) * rstd * g.x + b.x;
  o.y = (v.y - mean) * rstd * g.y + b.y;
  o.z = (v.z - mean) * rstd * g.z + b.z;
  o.w = (v.w - mean) * rstd * g.w + b.w;
  *(float4*)(out + base + t * 4) = o;
}

extern "C" void kernel_launch(void* const* d_in, const int* in_sizes, int n_in,
                              void* d_out, int out_size, void* d_ws, size_t ws_size,
                              hipStream_t stream) {
  (void)in_sizes; (void)n_in; (void)out_size;
  const float* x     = (const float*)d_in[0];  // [4096,1024]
  const float* W     = (const float*)d_in[1];  // [16,1024,1024]
  const float* bias  = (const float*)d_in[2];  // [16,1024]
  const float* amp   = (const float*)d_in[3];  // [16,1024]
  const float* phase = (const float*)d_in[4];  // [16,1024]
  const float* gamma = (const float*)d_in[5];  // [1024]
  const float* beta  = (const float*)d_in[6];  // [1024]
  float* out = (float*)d_out;                  // [4096,16,1024] = 256 MiB

  const bool big = ws_size >= (size_t)134217728ULL;  // bf16 sup fits in ws

  unsigned short *Wt, *xbuf, *supb = nullptr;
  float *mixp, *bmixp;
  if (big) {
    // scratch Wt/xb/mix live in d_out (fully rewritten by LN afterwards);
    // ws holds bf16 sup (exactly 128 MiB)
    char* ob = (char*)d_out;
    Wt    = (unsigned short*)ob;                    // 32 MiB
    xbuf  = (unsigned short*)(ob + 33554432);       //  8 MiB
    mixp  = (float*)(ob + 41943040);                // 64 KiB
    bmixp = mixp + 16384;                           // 64 KiB
    supb  = (unsigned short*)d_ws;                  // 128 MiB
  } else {
    char* ws = (char*)d_ws;
    Wt    = (unsigned short*)ws;
    xbuf  = (unsigned short*)(ws + 33554432);
    mixp  = (float*)(ws + 33554432 + 8388608);
    bmixp = mixp + 16384;
  }

  hipLaunchKernelGGL(mix_kernel, dim3(4), dim3(256), 0, stream, amp, phase, bias, mixp, bmixp);
  hipLaunchKernelGGL(cast_x_kernel, dim3(4096), dim3(256), 0, stream, x, xbuf);
  hipLaunchKernelGGL(transpose_w_kernel, dim3(16, 16, 16), dim3(256), 0, stream, W, mixp, Wt);
  if (big) {
    hipLaunchKernelGGL((gemm_kernel<true>), dim3(128, 32), dim3(256), 0, stream,
                       xbuf, Wt, bmixp, out, supb);
    hipLaunchKernelGGL(ln_bf16_kernel, dim3(65536), dim3(256), 0, stream,
                       supb, out, gamma, beta);
  } else {
    hipLaunchKernelGGL((gemm_kernel<false>), dim3(128, 32), dim3(256), 0, stream,
                       xbuf, Wt, bmixp, out, nullptr);
    hipLaunchKernelGGL(ln_kernel, dim3(65536), dim3(256), 0, stream, out, gamma, beta);
  }
}

// Round 9
// 299.996 us; speedup vs baseline: 1.1590x; 1.0085x over previous
//
#include <hip/hip_runtime.h>

typedef __attribute__((ext_vector_type(8))) short short8;
typedef __attribute__((ext_vector_type(4))) float f32x4;
typedef __attribute__((ext_vector_type(4))) unsigned short u16x4;

#define GLOAD16(g, l)                                                          \
  __builtin_amdgcn_global_load_lds(                                            \
      (const __attribute__((address_space(1))) unsigned int*)(g),              \
      (__attribute__((address_space(3))) unsigned int*)(l), 16, 0, 0)

__device__ __forceinline__ unsigned short f2bf(float f) {
  unsigned int u = __float_as_uint(f);
  u += 0x7FFFu + ((u >> 16) & 1u);   // RNE
  return (unsigned short)(u >> 16);
}
__device__ __forceinline__ float bf2f(unsigned short h) {
  return __uint_as_float(((unsigned int)h) << 16);
}

// ---------------------------------------------------------------- mix / bmix
__global__ void mix_kernel(const float* __restrict__ amp,
                           const float* __restrict__ phase,
                           const float* __restrict__ bias,
                           float* __restrict__ mix, float* __restrict__ bmix) {
  int q = blockIdx.x * blockDim.x + threadIdx.x;  // 0..1023
  float a[16];
  float mx = -1e30f;
  for (int s = 0; s < 16; ++s) {
    a[s] = amp[s * 1024 + q];
    mx = fmaxf(mx, a[s]);
  }
  float sum = 0.f;
  for (int s = 0; s < 16; ++s) {
    a[s] = __expf(a[s] - mx);
    sum += a[s];
  }
  float inv = 1.f / sum;
  for (int s = 0; s < 16; ++s) {
    float m = a[s] * inv * cosf(phase[s * 1024 + q]);
    mix[s * 1024 + q] = m;
    bmix[s * 1024 + q] = bias[s * 1024 + q] * m;
  }
}

// ---------------------------------------------------------------- cast x->bf16
__global__ void cast_x_kernel(const float* __restrict__ x,
                              unsigned short* __restrict__ xb) {
  int i = (blockIdx.x * blockDim.x + threadIdx.x) * 4;
  float4 v = *(const float4*)(x + i);
  union { unsigned short h[4]; uint2 u; } o;
  o.h[0] = f2bf(v.x); o.h[1] = f2bf(v.y); o.h[2] = f2bf(v.z); o.h[3] = f2bf(v.w);
  *(uint2*)(xb + i) = o.u;
}

// ------------------------------------------- transpose+cast+scale W -> Wt bf16
// Wt[s][q][i] = bf16( W[s][i][q] * mix[s][q] )
__global__ __launch_bounds__(256) void transpose_w_kernel(
    const float* __restrict__ W, const float* __restrict__ mix,
    unsigned short* __restrict__ Wt) {
  __shared__ unsigned short tile[64][66];
  const int s = blockIdx.z;
  const int q0 = blockIdx.x * 64, i0 = blockIdx.y * 64;
  const int t = threadIdx.x;
  const float* Ws = W + (size_t)s * 1048576;
  unsigned short* Wts = Wt + (size_t)s * 1048576;
  const int rq = t & 63, ri = t >> 6;
  const float mv = mix[s * 1024 + q0 + rq];
  #pragma unroll
  for (int p = 0; p < 16; ++p)
    tile[p * 4 + ri][rq] =
        f2bf(Ws[(size_t)(i0 + p * 4 + ri) * 1024 + q0 + rq] * mv);
  __syncthreads();
  const int wq = t >> 3, wi = (t & 7) * 8;
  #pragma unroll
  for (int o = 0; o < 2; ++o) {
    union { unsigned short h[8]; short8 v; } u;
    #pragma unroll
    for (int e = 0; e < 8; ++e) u.h[e] = tile[wi + e][o * 32 + wq];
    *(short8*)(Wts + (size_t)(q0 + o * 32 + wq) * 1024 + i0 + wi) = u.v;
  }
}

// ---------------------------------------------------------------- bf16 GEMM
// R8 + TRUE counted-vmcnt (T4): raw s_barrier with explicit waits so the
// stage for tile kt+2 stays in flight ACROSS the barrier (no __syncthreads
// drain-to-0).  Per step:
//   STAGE(kt+2) ; ds_reads(cur) ; lgkmcnt(0) ; vmcnt(4) ; s_barrier ; MFMA
// Invariants: lgkmcnt(0) pre-barrier => all reads of buf cur drained before
// the barrier that releases the overwriting STAGE (next step, same buf);
// vmcnt(4) pre-barrier (outstanding = stages kt+1,kt+2 = 8) => tile kt+1
// landed, barrier joins per-wave confirmations.  MFMA after barrier is
// register-only (intra-wave dep already satisfied).  Tail: kt=30 vmcnt(0).
template <bool BF16SUP>
__global__ __launch_bounds__(256) void gemm_kernel(
    const unsigned short* __restrict__ xb, const unsigned short* __restrict__ wt,
    const float* __restrict__ bmix,
    float* __restrict__ outf, unsigned short* __restrict__ sup) {
  __shared__ __align__(16) unsigned short Abuf[3][128 * 32];
  __shared__ __align__(16) unsigned short Bbuf[3][128 * 32];

  const int tid = threadIdx.x;
  const int lane = tid & 63;
  const int wv = tid >> 6;
  const int wm = wv >> 1, wn = wv & 1;
  const int m0 = blockIdx.y * 128;
  const int n0 = blockIdx.x * 128;

  const int c0 = tid, c1 = tid + 256;
  const int r0 = c0 >> 2, k80 = (c0 & 3) * 8;
  const int r1 = c1 >> 2, k81 = (c1 & 3) * 8;
  const unsigned short* ga0 = xb + (size_t)(m0 + r0) * 1024 + k80;
  const unsigned short* ga1 = xb + (size_t)(m0 + r1) * 1024 + k81;
  const unsigned short* gb0 = wt + (size_t)(n0 + r0) * 1024 + k80;
  const unsigned short* gb1 = wt + (size_t)(n0 + r1) * 1024 + k81;

#define STAGE(kt, b) do {                                                      \
    const int _ko = (kt) * 32;                                                 \
    GLOAD16(ga0 + _ko, &Abuf[b][c0 * 8]);                                      \
    GLOAD16(ga1 + _ko, &Abuf[b][c1 * 8]);                                      \
    GLOAD16(gb0 + _ko, &Bbuf[b][c0 * 8]);                                      \
    GLOAD16(gb1 + _ko, &Bbuf[b][c1 * 8]);                                      \
  } while (0)

  f32x4 acc[4][4];
  #pragma unroll
  for (int i = 0; i < 4; ++i)
    #pragma unroll
    for (int j = 0; j < 4; ++j) acc[i][j] = (f32x4){0.f, 0.f, 0.f, 0.f};

  // prologue: stage tiles 0,1; wait tile 0 landed (tile 1 stays in flight)
  STAGE(0, 0);
  STAGE(1, 1);
  asm volatile("s_waitcnt vmcnt(4)" ::: "memory");
  __builtin_amdgcn_s_barrier();

  const int lr = lane & 15;
  const int lk = (lane >> 4) * 8;
  int cur = 0;
  for (int kt = 0; kt < 32; ++kt) {
    if (kt < 30) {
      int nb = cur + 2; if (nb >= 3) nb -= 3;
      STAGE(kt + 2, nb);
    }
    short8 af[4], bfr[4];
    #pragma unroll
    for (int mi = 0; mi < 4; ++mi)
      af[mi] = *(const short8*)&Abuf[cur][(wm * 64 + mi * 16 + lr) * 32 + lk];
    #pragma unroll
    for (int ni = 0; ni < 4; ++ni)
      bfr[ni] = *(const short8*)&Bbuf[cur][(wn * 64 + ni * 16 + lr) * 32 + lk];
    // drain my LDS reads, then wait next tile landed, then barrier (loads
    // for tile kt+2 remain in flight across it)
    asm volatile("s_waitcnt lgkmcnt(0)" ::: "memory");
    if (kt < 30) {
      asm volatile("s_waitcnt vmcnt(4)" ::: "memory");
    } else if (kt == 30) {
      asm volatile("s_waitcnt vmcnt(0)" ::: "memory");
    }
    __builtin_amdgcn_sched_barrier(0);
    __builtin_amdgcn_s_barrier();
    #pragma unroll
    for (int mi = 0; mi < 4; ++mi)
      #pragma unroll
      for (int ni = 0; ni < 4; ++ni)
        acc[mi][ni] = __builtin_amdgcn_mfma_f32_16x16x32_bf16(
            af[mi], bfr[ni], acc[mi][ni], 0, 0, 0);
    cur += 1; if (cur >= 3) cur = 0;
  }
#undef STAGE

  // epilogue: sup = acc + bmix  (mix folded into Wt)
  #pragma unroll
  for (int ni = 0; ni < 4; ++ni) {
    const int n = n0 + wn * 64 + ni * 16 + lr;
    const float bv = bmix[n];
    #pragma unroll
    for (int mi = 0; mi < 4; ++mi) {
      const int m = m0 + wm * 64 + mi * 16 + (lane >> 4) * 4;
      #pragma unroll
      for (int r = 0; r < 4; ++r) {
        float v = acc[mi][ni][r] + bv;
        if (BF16SUP)
          sup[(size_t)(m + r) * 16384 + n] = f2bf(v);
        else
          outf[(size_t)(m + r) * 16384 + n] = v;
      }
    }
  }
}

// ------------------------------------------------------- LN from bf16 sup
__global__ __launch_bounds__(256) void ln_bf16_kernel(
    const unsigned short* __restrict__ sup, float* __restrict__ out,
    const float* __restrict__ gamma, const float* __restrict__ beta) {
  __shared__ float red[8];
  const int t = threadIdx.x;
  const size_t base = (size_t)blockIdx.x * 1024;
  u16x4 raw = *(const u16x4*)(sup + base + t * 4);
  float v[4];
  #pragma unroll
  for (int j = 0; j < 4; ++j) v[j] = bf2f(raw[j]);
  float s = v[0] + v[1] + v[2] + v[3];
  float ss = v[0] * v[0] + v[1] * v[1] + v[2] * v[2] + v[3] * v[3];
  #pragma unroll
  for (int m = 32; m >= 1; m >>= 1) {
    s += __shfl_xor(s, m);
    ss += __shfl_xor(ss, m);
  }
  const int wv = t >> 6;
  if ((t & 63) == 0) { red[wv * 2] = s; red[wv * 2 + 1] = ss; }
  __syncthreads();
  const float S = red[0] + red[2] + red[4] + red[6];
  const float SS = red[1] + red[3] + red[5] + red[7];
  const float mean = S * (1.0f / 1024.0f);
  const float var = SS * (1.0f / 1024.0f) - mean * mean;
  const float rstd = rsqrtf(var + 1e-5f);
  const float4 g = *(const float4*)(gamma + t * 4);
  const float4 b = *(const float4*)(beta + t * 4);
  float4 o;
  o.x = (v[0] - mean) * rstd * g.x + b.x;
  o.y = (v[1] - mean) * rstd * g.y + b.y;
  o.z = (v[2] - mean) * rstd * g.z + b.z;
  o.w = (v[3] - mean) * rstd * g.w + b.w;
  *(float4*)(out + base + t * 4) = o;
}

// ------------------------------------------------------- in-place f32 LN
__global__ __launch_bounds__(256) void ln_kernel(float* __restrict__ out,
                                                 const float* __restrict__ gamma,
                                                 const float* __restrict__ beta) {
  __shared__ float red[8];
  const int t = threadIdx.x;
  const size_t base = (size_t)blockIdx.x * 1024;
  float4 v = *(const float4*)(out + base + t * 4);
  float s = v.x + v.y + v.z + v.w;
  float ss = v.x * v.x + v.y * v.y + v.z * v.z + v.w * v.w;
  #pragma unroll
  for (int m = 32; m >= 1; m >>= 1) {
    s += __shfl_xor(s, m);
    ss += __shfl_xor(ss, m);
  }
  const int wv = t >> 6;
  if ((t & 63) == 0) { red[wv * 2] = s; red[wv * 2 + 1] = ss; }
  __syncthreads();
  const float S = red[0] + red[2] + red[4] + red[6];
  const float SS = red[1] + red[3] + red[5] + red[7];
  const float mean = S * (1.0f / 1024.0f);
  const float var = SS * (1.0f / 1024.0f) - mean * mean;
  const float rstd = rsqrtf(var + 1e-5f);
  const float4 g = *(const float4*)(gamma + t * 4);
  const float4 b = *(const float4*)(beta + t * 4);
  float4 o;
  o.x = (v.x - mean) * rstd * g.x + b.x;
  o.y = (v.y - mean) * rstd * g.y + b.y;
  o.z = (v.z - mean) * rstd * g.z + b.z;
  o.w = (v.w - mean) * rstd * g.w + b.w;
  *(float4*)(out + base + t * 4) = o;
}

extern "C" void kernel_launch(void* const* d_in, const int* in_sizes, int n_in,
                              void* d_out, int out_size, void* d_ws, size_t ws_size,
                              hipStream_t stream) {
  (void)in_sizes; (void)n_in; (void)out_size;
  const float* x     = (const float*)d_in[0];  // [4096,1024]
  const float* W     = (const float*)d_in[1];  // [16,1024,1024]
  const float* bias  = (const float*)d_in[2];  // [16,1024]
  const float* amp   = (const float*)d_in[3];  // [16,1024]
  const float* phase = (const float*)d_in[4];  // [16,1024]
  const float* gamma = (const float*)d_in[5];  // [1024]
  const float* beta  = (const float*)d_in[6];  // [1024]
  float* out = (float*)d_out;                  // [4096,16,1024] = 256 MiB

  const bool big = ws_size >= (size_t)134217728ULL;  // bf16 sup fits in ws

  unsigned short *Wt, *xbuf, *supb = nullptr;
  float *mixp, *bmixp;
  if (big) {
    // scratch Wt/xb/mix live in d_out (fully rewritten by LN afterwards);
    // ws holds bf16 sup (exactly 128 MiB)
    char* ob = (char*)d_out;
    Wt    = (unsigned short*)ob;                    // 32 MiB
    xbuf  = (unsigned short*)(ob + 33554432);       //  8 MiB
    mixp  = (float*)(ob + 41943040);                // 64 KiB
    bmixp = mixp + 16384;                           // 64 KiB
    supb  = (unsigned short*)d_ws;                  // 128 MiB
  } else {
    char* ws = (char*)d_ws;
    Wt    = (unsigned short*)ws;
    xbuf  = (unsigned short*)(ws + 33554432);
    mixp  = (float*)(ws + 33554432 + 8388608);
    bmixp = mixp + 16384;
  }

  hipLaunchKernelGGL(mix_kernel, dim3(4), dim3(256), 0, stream, amp, phase, bias, mixp, bmixp);
  hipLaunchKernelGGL(cast_x_kernel, dim3(4096), dim3(256), 0, stream, x, xbuf);
  hipLaunchKernelGGL(transpose_w_kernel, dim3(16, 16, 16), dim3(256), 0, stream, W, mixp, Wt);
  if (big) {
    hipLaunchKernelGGL((gemm_kernel<true>), dim3(128, 32), dim3(256), 0, stream,
                       xbuf, Wt, bmixp, out, supb);
    hipLaunchKernelGGL(ln_bf16_kernel, dim3(65536), dim3(256), 0, stream,
                       supb, out, gamma, beta);
  } else {
    hipLaunchKernelGGL((gemm_kernel<false>), dim3(128, 32), dim3(256), 0, stream,
                       xbuf, Wt, bmixp, out, nullptr);
    hipLaunchKernelGGL(ln_kernel, dim3(65536), dim3(256), 0, stream, out, gamma, beta);
  }
}